// Round 11
// baseline (262.740 us; speedup 1.0000x reference)
//
#include <hip/hip_runtime.h>

// ---------------------------------------------------------------------------
// Fused causal attention, MI355X gfx950.
// cast fp32->f16 -> QKV GEMM -> V transpose -> flash attention (strip-paired
// uniform blocks, dbuf gld16 K/V, operand-swap, no spills) -> out GEMM.
// MFMA 16x16x32 layouts (m89/m91/m120-verified):
//   A-frag: A[m=lane&15][k=(lane>>4)*8+j], j=0..7
//   B-frag: B[k=(lane>>4)*8+j][n=lane&15]
//   C/D   : row=(lane>>4)*4+reg, col=lane&15
// Attention swap: St = K*Q^T (C: row=key,col=q), O^T = V^T*P.
// R1: K/V LDS in fragment order (gld16 w/ per-lane pre-permuted global src).
// R2: P St->PV handoff in-register via permlane32/16_swap; setprio on MFMA.
// R3: attn XCD/bh-clustering swizzle; exp2-domain softmax; defer-max THR=0.
// R6: gemm line-merged staging + chunk-XOR source swizzle; ring-3 pipeline.
// R7-R10: pkrtz P path, permlane epilogue (no Ps LDS); scratch bugs fixed
//     (no big lambdas -> no outlining; all arrays constant-indexed).
//     Dual-strip ILP verdict: only +3% -> VALU count not binding.
// R11: UNIFORM-33 schedule (tail fix). Occupancy was 36.5% vs 50% resident
//     max: grid == capacity (1024 blocks, 4/CU, no backfill) but iteration
//     counts varied 17..32 -> CUs drained for the last ~20% of the kernel.
//     Now each block runs strip B (kt=0..qtB) then strip A (kt=0..qtA) as
//     33 IDENTICAL single-strip iterations -> all blocks finish together,
//     16 waves/CU for the whole kernel. Step body is a macro (not a lambda).
// ---------------------------------------------------------------------------

typedef _Float16 f16x8 __attribute__((ext_vector_type(8)));
typedef __fp16 fp16x2 __attribute__((ext_vector_type(2)));
typedef float floatx4 __attribute__((ext_vector_type(4)));
typedef unsigned int uint2v __attribute__((ext_vector_type(2)));

union U4H8 { uint4 u; f16x8 h; };

__device__ __forceinline__ ushort f32_to_h_bits(float f) {
  _Float16 h = (_Float16)f;
  return __builtin_bit_cast(ushort, h);
}
__device__ __forceinline__ uint pack2h(float a, float b) {
  return (uint)f32_to_h_bits(a) | ((uint)f32_to_h_bits(b) << 16);
}
__device__ __forceinline__ uint pkrtz(float a, float b) {
  fp16x2 r = __builtin_amdgcn_cvt_pkrtz(a, b);
  return __builtin_bit_cast(uint, r);
}
// bare 2^x (one v_exp_f32, no libm guards)
__device__ __forceinline__ float exp2_fast(float x) {
  float r;
  asm("v_exp_f32 %0, %1" : "=v"(r) : "v"(x));
  return r;
}

// quad-permutation: C-layout quad rows -> B-frag/rowmajor 8-elem runs
// lane(quad,l15) gets elems quad*8+j of the 32-block (proven in R2 P-path).
__device__ __forceinline__ uint4 qtrans(uint pA, uint pB, uint pC, uint pD) {
  uint2v ac = __builtin_amdgcn_permlane32_swap(pA, pC, false, false);
  uint2v bd = __builtin_amdgcn_permlane32_swap(pB, pD, false, false);
  uint2v ac2 = __builtin_amdgcn_permlane16_swap(ac[0], ac[1], false, false);
  uint2v bd2 = __builtin_amdgcn_permlane16_swap(bd[0], bd[1], false, false);
  return (uint4){ac2[0], bd2[0], ac2[1], bd2[1]};
}

// async global->LDS, 16B/lane; LDS dest = wave-uniform base + lane*16
__device__ __forceinline__ void gld16(const void* g, void* l) {
  __builtin_amdgcn_global_load_lds(
      (const __attribute__((address_space(1))) unsigned char*)g,
      (__attribute__((address_space(3))) unsigned char*)l, 16, 0, 0);
}

// ---------------------------------------------------------------- cast kernel
__global__ __launch_bounds__(256) void cast_f32_f16(const float* __restrict__ in,
                                                    ushort* __restrict__ out) {
  int i = blockIdx.x * 256 + threadIdx.x;
  float4 v = ((const float4*)in)[i];
  ushort4 o;
  o.x = f32_to_h_bits(v.x);
  o.y = f32_to_h_bits(v.y);
  o.z = f32_to_h_bits(v.z);
  o.w = f32_to_h_bits(v.w);
  ((ushort4*)out)[i] = o;
}

// ------------------------------------------------------------------ GEMM B^T
// C[M,N] = A[M,K] * B[N,K]^T.  128x128 tile, BK=32, 4 waves 2x2, 4x4 MFMA.
// Depth-2 ring pipeline: 3 LDS buffers; per step: vmcnt(4) waits ONLY the
// oldest tile's loads, s_barrier, stage(t+2), frag reads, 16 MFMA.
// Staging (line-merged + source-swizzled): lane l loads
//   A[m0 + w*16 + (l>>2)][16B-chunk (l&3)^((l>>3)&3)]
// into linear LDS slot lane*16 -> LDS holds row-major [row][32] with
// physical chunk p containing logical chunk p^((row>>1)&3).
// Reads: logical chunk quad at row R -> physical quad^((R>>1)&3), R%16=l15.
template <int OUT_F16>
__global__ __launch_bounds__(256) void gemm_bt(const ushort* __restrict__ A,
                                               const ushort* __restrict__ B,
                                               void* __restrict__ Cv,
                                               int M, int N, int K) {
  __shared__ ushort As[3][4096];
  __shared__ ushort Bs[3][4096];

  const int tid = threadIdx.x;
  const int lane = tid & 63;
  const int w = tid >> 6;
  const int l15 = lane & 15;
  const int quad = lane >> 4;

  // bijective XCD chunk swizzle (requires gx*gy % 8 == 0): XCD k = lin&7
  // owns contiguous by-panels [8k, 8k+8) across all bx.
  const int gx = gridDim.x;
  const int lin = blockIdx.y * gx + blockIdx.x;
  const int qq = (gx * gridDim.y) >> 3;
  const int nl = (lin & 7) * qq + (lin >> 3);
  const int m0 = (nl / gx) * 128;
  const int n0 = (nl % gx) * 128;

  const int wm = (w & 1) * 64;
  const int wn = (w >> 1) * 64;

  floatx4 acc[4][4];
#pragma unroll
  for (int i = 0; i < 4; i++)
#pragma unroll
    for (int j = 0; j < 4; j++) acc[i][j] = (floatx4){0.f, 0.f, 0.f, 0.f};

  // staging source: row w*16 + (l>>2) (4 adjacent lanes share one 64B line),
  // chunk XOR-swizzled so linear LDS dest yields the swizzled layout.
  const int srow = w * 16 + (lane >> 2);
  const int sq = ((lane & 3) ^ ((lane >> 3) & 3)) * 8;
  const ushort* Ap = A + (size_t)(m0 + srow) * K + sq;
  const ushort* Bp = B + (size_t)(n0 + srow) * K + sq;
  const size_t rstep = (size_t)64 * K;

  auto stage = [&](int k0, int buf) {
    gld16(Ap + k0, &As[buf][w * 512]);
    gld16(Ap + rstep + k0, &As[buf][(w + 4) * 512]);
    gld16(Bp + k0, &Bs[buf][w * 512]);
    gld16(Bp + rstep + k0, &Bs[buf][(w + 4) * 512]);
  };

  stage(0, 0);
  stage(32, 1);

  const int psw = (quad ^ ((l15 >> 1) & 3)) * 8;  // physical chunk for reads

  int bt = 0;   // buffer of tile t
  int bs = 2;   // buffer of tile t+2
  for (int k0 = 0; k0 < K; k0 += 32) {
    // steady state: 8 loads outstanding (tiles t, t+1); wait only tile t's 4.
    if (k0 + 64 < K) {
      asm volatile("s_waitcnt vmcnt(4)" ::: "memory");
    } else {
      asm volatile("s_waitcnt vmcnt(0)" ::: "memory");
    }
    __builtin_amdgcn_s_barrier();
    asm volatile("" ::: "memory");
    if (k0 + 64 < K) stage(k0 + 64, bs);

    U4H8 af[4], bf[4];
#pragma unroll
    for (int mi = 0; mi < 4; mi++)
      af[mi].u = *(const uint4*)&As[bt][(wm + mi * 16 + l15) * 32 + psw];
#pragma unroll
    for (int ni = 0; ni < 4; ni++)
      bf[ni].u = *(const uint4*)&Bs[bt][(wn + ni * 16 + l15) * 32 + psw];
#pragma unroll
    for (int mi = 0; mi < 4; mi++)
#pragma unroll
      for (int ni = 0; ni < 4; ni++)
        acc[mi][ni] = __builtin_amdgcn_mfma_f32_16x16x32_f16(af[mi].h, bf[ni].h,
                                                             acc[mi][ni], 0, 0, 0);
    bt = (bt == 2) ? 0 : bt + 1;
    bs = (bs == 2) ? 0 : bs + 1;
  }

#pragma unroll
  for (int mi = 0; mi < 4; mi++) {
#pragma unroll
    for (int r = 0; r < 4; r++) {
      size_t row = m0 + wm + mi * 16 + quad * 4 + r;
#pragma unroll
      for (int ni = 0; ni < 4; ni++) {
        size_t col = n0 + wn + ni * 16 + l15;
        float v = acc[mi][ni][r];
        if (OUT_F16)
          ((ushort*)Cv)[row * N + col] = f32_to_h_bits(v);
        else
          ((float*)Cv)[row * N + col] = v;
      }
    }
  }
}

// --------------------------------------------------------------- V transpose
// qkv [8192][3072] f16 -> vtg[bh=64][dh=64][key=2048] f16.
__global__ __launch_bounds__(256) void vtrans(const ushort* __restrict__ qkv,
                                              ushort* __restrict__ vtg) {
  __shared__ ushort T[64 * 66];
  const int tid = threadIdx.x;
  const int kt = blockIdx.x;
  const int bh = blockIdx.y;
  const int b = bh >> 4, h = bh & 15;

  const int r = tid >> 3;
  const int c = (tid & 7) * 8;
  const ushort* src = qkv + (size_t)(b * 2048 + kt * 64) * 3072 + 2048 + h * 64;
  uint4 v0 = *(const uint4*)(src + (size_t)r * 3072 + c);
  uint4 v1 = *(const uint4*)(src + (size_t)(r + 32) * 3072 + c);
  union { uint4 u; ushort s[8]; } a0, a1;
  a0.u = v0; a1.u = v1;
#pragma unroll
  for (int j = 0; j < 8; j++) {
    T[(c + j) * 66 + r] = a0.s[j];
    T[(c + j) * 66 + r + 32] = a1.s[j];
  }
  __syncthreads();

  const int d = tid >> 3;
  const int kc = (tid & 7) * 8;
  ushort* dst = vtg + (size_t)bh * 64 * 2048 + (size_t)kt * 64;
  union { uint u[4]; uint4 u4; } o0, o1;
#pragma unroll
  for (int i = 0; i < 4; i++) {
    o0.u[i] = *(const uint*)&T[d * 66 + kc + 2 * i];
    o1.u[i] = *(const uint*)&T[(d + 32) * 66 + kc + 2 * i];
  }
  *(uint4*)(dst + (size_t)d * 2048 + kc) = o0.u4;
  *(uint4*)(dst + (size_t)(d + 32) * 2048 + kc) = o1.u4;
}

// ---- one single-strip attention step (macro: must inline, rule R8/R9).
// Reads K/V frags from LDS buf, does St=K*Q^T, online softmax (exp2 domain,
// defer-max THR=0), P->B-frag via pkrtz+qtrans, O^T += V^T*P.
#define ATTN_STEP(QF, Q0V, MV, LV, OA, KT64, BUF, DIAG)                        \
  do {                                                                         \
    floatx4 ss[4];                                                             \
    __builtin_amdgcn_s_setprio(1);                                             \
    _Pragma("unroll") for (int t = 0; t < 4; t++) {                            \
      U4H8 kfa, kfb;                                                           \
      kfa.u = *(const uint4*)&Ks[BUF][(t * 2 + 0) * 512 + lane * 8];           \
      kfb.u = *(const uint4*)&Ks[BUF][(t * 2 + 1) * 512 + lane * 8];           \
      floatx4 aa = (floatx4){0.f, 0.f, 0.f, 0.f};                              \
      aa = __builtin_amdgcn_mfma_f32_16x16x32_f16(kfa.h, QF[0].h, aa, 0, 0, 0);\
      aa = __builtin_amdgcn_mfma_f32_16x16x32_f16(kfb.h, QF[1].h, aa, 0, 0, 0);\
      ss[t] = aa;                                                              \
    }                                                                          \
    __builtin_amdgcn_s_setprio(0);                                             \
    if (DIAG) {                                                                \
      const int qv = (Q0V) + l15;                                              \
      _Pragma("unroll") for (int t = 0; t < 4; t++)                            \
          _Pragma("unroll") for (int r = 0; r < 4; r++) {                      \
        int key = (KT64) + t * 16 + quad * 4 + r;                              \
        if (key > qv) ss[t][r] = -1e30f;                                       \
      }                                                                        \
    }                                                                          \
    float fa = fmaxf(fmaxf(ss[0][0], ss[0][1]), fmaxf(ss[0][2], ss[0][3]));    \
    float fb = fmaxf(fmaxf(ss[1][0], ss[1][1]), fmaxf(ss[1][2], ss[1][3]));    \
    float fc = fmaxf(fmaxf(ss[2][0], ss[2][1]), fmaxf(ss[2][2], ss[2][3]));    \
    float fd = fmaxf(fmaxf(ss[3][0], ss[3][1]), fmaxf(ss[3][2], ss[3][3]));    \
    float tm = fmaxf(fmaxf(fa, fb), fmaxf(fc, fd));                            \
    tm = fmaxf(tm, __shfl_xor(tm, 16));                                        \
    tm = fmaxf(tm, __shfl_xor(tm, 32));                                        \
    if (__any(tm > (MV))) {                                                    \
      float mnew = fmaxf((MV), tm);                                            \
      float alpha = exp2_fast((MV)-mnew);                                      \
      (MV) = mnew;                                                             \
      (LV) *= alpha;                                                           \
      _Pragma("unroll") for (int ni = 0; ni < 4; ni++) OA[ni] *= alpha;        \
    }                                                                          \
    {                                                                          \
      const float mm = (MV);                                                   \
      float rs = 0.f;                                                          \
      _Pragma("unroll") for (int t = 0; t < 4; t++)                            \
          _Pragma("unroll") for (int r = 0; r < 4; r++) {                      \
        float p = exp2_fast(ss[t][r] - mm);                                    \
        ss[t][r] = p;                                                          \
        rs += p;                                                               \
      }                                                                        \
      rs += __shfl_xor(rs, 16);                                                \
      rs += __shfl_xor(rs, 32);                                                \
      (LV) += rs;                                                              \
    }                                                                          \
    _Pragma("unroll") for (int kc = 0; kc < 2; kc++) {                         \
      U4H8 pb;                                                                 \
      pb.u = qtrans(pkrtz(ss[kc * 2][0], ss[kc * 2][1]),                       \
                    pkrtz(ss[kc * 2][2], ss[kc * 2][3]),                       \
                    pkrtz(ss[kc * 2 + 1][0], ss[kc * 2 + 1][1]),               \
                    pkrtz(ss[kc * 2 + 1][2], ss[kc * 2 + 1][3]));              \
      __builtin_amdgcn_s_setprio(1);                                           \
      _Pragma("unroll") for (int ni = 0; ni < 4; ni++) {                       \
        U4H8 vf;                                                               \
        vf.u = *(const uint4*)&Vs[BUF][(ni * 2 + kc) * 512 + lane * 8];        \
        OA[ni] =                                                               \
            __builtin_amdgcn_mfma_f32_16x16x32_f16(vf.h, pb.h, OA[ni], 0, 0, 0);\
      }                                                                        \
      __builtin_amdgcn_s_setprio(0);                                           \
    }                                                                          \
  } while (0)

// ------------------------------------------------------------ flash attention
// Block = strip pair (bx, 31-bx); UNIFORM-33 schedule: strip B (kt=0..qtB)
// then strip A (kt=0..qtA), 33 identical single-strip iterations per block.
// 1-D grid 1024; decode: xcd=id&7 owns 8 bh (K/V ~4MB L2-resident).
// K/V double-buffered via gld16; LDS fragment order (sub*64+lane chunks).
__global__ __launch_bounds__(256, 4) void attn_fused(const ushort* __restrict__ qkv,
                                                     const ushort* __restrict__ vtg,
                                                     ushort* __restrict__ attn_out) {
  __shared__ ushort Ks[2][4096];        // [buf][(t*2+kc)*512 + lane*8]  16 KB
  __shared__ ushort Vs[2][4096];        // [buf][(ni*2+kc)*512 + lane*8] 16 KB

  const int tid = threadIdx.x;
  const int lane = tid & 63;
  const int w = tid >> 6;
  const int l15 = lane & 15;
  const int quad = lane >> 4;
  const int id = blockIdx.x;            // 0..1023
  const int n_ = id >> 3;
  const int bx = n_ >> 3;               // 0..15
  const int bh = (id & 7) * 8 + (n_ & 7);
  const int b = bh >> 4;
  const int h = bh & 15;
  const int bS = b * 2048;
  const int qtA = bx;
  const int qtB = 31 - bx;
  const int q0A = qtA * 64 + w * 16;    // strip A q-granule base
  const int q0B = qtB * 64 + w * 16;    // strip B q-granule base

  // Q B-frags (B[k=dh][n=q] == Q[q][dh]), pre-scaled by log2(e)/sqrt(64)
  // (exp2-domain softmax: S2 = S * log2e, p = 2^(S2 - m2)).
  U4H8 qf0[2], qf1[2];
  {
    const ushort* qrowA = qkv + (size_t)(bS + q0A + l15) * 3072 + h * 64;
    const ushort* qrowB = qkv + (size_t)(bS + q0B + l15) * 3072 + h * 64;
#pragma unroll
    for (int kc = 0; kc < 2; kc++) {
      qf0[kc].u = *(const uint4*)(qrowA + kc * 32 + quad * 8);
      qf0[kc].h = qf0[kc].h * (_Float16)0.1803368787f;  // 0.125*log2(e)
      qf1[kc].u = *(const uint4*)(qrowB + kc * 32 + quad * 8);
      qf1[kc].h = qf1[kc].h * (_Float16)0.1803368787f;
    }
  }

  floatx4 o0[4], o1[4];  // per strip; D: dh=ni*16+quad*4+r, q=l15
#pragma unroll
  for (int ni = 0; ni < 4; ni++) {
    o0[ni] = (floatx4){0.f, 0.f, 0.f, 0.f};
    o1[ni] = (floatx4){0.f, 0.f, 0.f, 0.f};
  }
  float m0v = -1e30f, m1v = -1e30f, l0v = 0.f, l1v = 0.f;

  const ushort* kbase = qkv + (size_t)bS * 3072 + 1024 + h * 64;
  const ushort* vbase = vtg + (size_t)bh * 64 * 2048;
  const int sr = lane & 15;          // source row within 16-row granule
  const int scc = (lane >> 4) * 8;   // source 8-ushort chunk within 32

  // wave w stages key granule t=w of K and dh granule ni=w of V, in exact
  // fragment-read order (lane l -> row l&15, chunk l>>4).
  auto stage = [&](int kt, int buf) {
    const ushort* kg = kbase + (size_t)(kt * 64 + w * 16 + sr) * 3072 + scc;
    gld16(kg, &Ks[buf][(w * 2 + 0) * 512]);
    gld16(kg + 32, &Ks[buf][(w * 2 + 1) * 512]);
    const ushort* vg = vbase + (size_t)(w * 16 + sr) * 2048 + (size_t)kt * 64 + scc;
    gld16(vg, &Vs[buf][(w * 2 + 0) * 512]);
    gld16(vg + 32, &Vs[buf][(w * 2 + 1) * 512]);
  };

  stage(0, 0);
  int u = 0;  // global unit index 0..32 (buf parity)
  // ---- pass 1: strip B, kt = 0..qtB (17..32 iterations)
  for (int kt = 0; kt <= qtB; ++kt, ++u) {
    const int buf = u & 1;
    __syncthreads();  // drains vmcnt -> buf staged; prior LDS reads done
    stage(kt < qtB ? kt + 1 : 0, buf ^ 1);  // last iter stages pass-2 tile 0
    ATTN_STEP(qf1, q0B, m1v, l1v, o1, kt * 64, buf, kt == qtB);
  }
  // ---- pass 2: strip A, kt = 0..qtA (1..16 iterations); total always 33
  for (int kt = 0; kt <= qtA; ++kt, ++u) {
    const int buf = u & 1;
    __syncthreads();
    if (kt < qtA) stage(kt + 1, buf ^ 1);
    ATTN_STEP(qf0, q0A, m0v, l0v, o0, kt * 64, buf, kt == qtA);
  }

  // ---- epilogue: O^T -> row-major via qtrans (same permutation as P path);
  // lane(quad,l15) gets dh [p*32+quad*8, +8) of row q0+l15 -> 16B store.
  {
    float inv = 1.0f / l1v;
    ushort* orow = attn_out + (size_t)(bS + q0B + l15) * 1024 + h * 64;
#pragma unroll
    for (int p = 0; p < 2; p++) {
      uint4 x = qtrans(pack2h(o1[p * 2][0] * inv, o1[p * 2][1] * inv),
                       pack2h(o1[p * 2][2] * inv, o1[p * 2][3] * inv),
                       pack2h(o1[p * 2 + 1][0] * inv, o1[p * 2 + 1][1] * inv),
                       pack2h(o1[p * 2 + 1][2] * inv, o1[p * 2 + 1][3] * inv));
      *(uint4*)(orow + p * 32 + quad * 8) = x;
    }
  }
  {
    float inv = 1.0f / l0v;
    ushort* orow = attn_out + (size_t)(bS + q0A + l15) * 1024 + h * 64;
#pragma unroll
    for (int p = 0; p < 2; p++) {
      uint4 x = qtrans(pack2h(o0[p * 2][0] * inv, o0[p * 2][1] * inv),
                       pack2h(o0[p * 2][2] * inv, o0[p * 2][3] * inv),
                       pack2h(o0[p * 2 + 1][0] * inv, o0[p * 2 + 1][1] * inv),
                       pack2h(o0[p * 2 + 1][2] * inv, o0[p * 2 + 1][3] * inv));
      *(uint4*)(orow + p * 32 + quad * 8) = x;
    }
  }
}

// ---------------------------------------------------------------------- launch
extern "C" void kernel_launch(void* const* d_in, const int* in_sizes, int n_in,
                              void* d_out, int out_size, void* d_ws, size_t ws_size,
                              hipStream_t stream) {
  const float* x = (const float*)d_in[0];       // [4,2048,1024]
  const float* wqkv = (const float*)d_in[1];    // [3072,1024]
  const float* wo = (const float*)d_in[2];      // [1024,1024]
  float* out = (float*)d_out;                   // [4,2048,1024] fp32

  ushort* xh = (ushort*)d_ws;                          // 8192*1024
  ushort* wqkvh = xh + (size_t)8192 * 1024;            // 3072*1024
  ushort* woh = wqkvh + (size_t)3072 * 1024;           // 1024*1024
  ushort* qkvh = woh + (size_t)1024 * 1024;            // 8192*3072
  ushort* attnh = qkvh + (size_t)8192 * 3072;          // 8192*1024
  ushort* vtg = attnh + (size_t)8192 * 1024;           // 64*64*2048
  // total ws use: ~109 MB

  cast_f32_f16<<<8192, 256, 0, stream>>>(x, xh);
  cast_f32_f16<<<3072, 256, 0, stream>>>(wqkv, wqkvh);
  cast_f32_f16<<<1024, 256, 0, stream>>>(wo, woh);

  gemm_bt<1><<<dim3(24, 64), 256, 0, stream>>>(xh, wqkvh, qkvh, 8192, 3072, 1024);
  vtrans<<<dim3(32, 64), 256, 0, stream>>>(qkvh, vtg);
  attn_fused<<<dim3(1024), 256, 0, stream>>>(qkvh, vtg, attnh);
  gemm_bt<0><<<dim3(8, 64), 256, 0, stream>>>(attnh, woh, out, 8192, 1024, 1024);
}

// Round 12
// 260.957 us; speedup vs baseline: 1.0068x; 1.0068x over previous
//
#include <hip/hip_runtime.h>

// ---------------------------------------------------------------------------
// Fused causal attention, MI355X gfx950.
// cast fp32->f16 -> QKV GEMM -> V transpose -> flash attention (strip-paired
// dual-strip blocks, dbuf gld16 K/V, operand-swap, no spills) -> out GEMM.
// MFMA 16x16x32 layouts (m89/m91/m120-verified):
//   A-frag: A[m=lane&15][k=(lane>>4)*8+j], j=0..7
//   B-frag: B[k=(lane>>4)*8+j][n=lane&15]
//   C/D   : row=(lane>>4)*4+reg, col=lane&15
// Attention swap: St = K*Q^T (C: row=key,col=q), O^T = V^T*P.
// R1: K/V LDS in fragment order (gld16 w/ per-lane pre-permuted global src).
// R2: P St->PV handoff in-register via permlane32/16_swap; setprio on MFMA.
// R3: attn XCD/bh-clustering swizzle; exp2-domain softmax; defer-max THR=0.
// R6: gemm line-merged staging + chunk-XOR source swizzle; ring-3 pipeline.
// R7-R10: pkrtz P path, permlane epilogue; scratch bugs fixed (no big
//     lambdas, constant-indexed arrays). attn best = R10 dual-strip: 75.4us.
// R11: uniform-33 schedule REGRESSED (83.5us): +35% iteration fixed cost
//     outweighed tail savings. attn REVERTED to R10 here; attn is done.
// R12: GEMM occupancy fix (was 29% occ, 2-3 blocks/CU, latency-bound):
//     256x128 tile, 512 threads / 8 waves (4M x 2N), SAME per-wave inner
//     loop (4x4 frags, 16 MFMA, 8 ds_read). LDS ring-3 x 24KB = 72KB ->
//     2 blocks x 8 waves = 16 waves/CU. Staging 3 gld16/wave (vmcnt 3/6).
//     B HBM traffic halves (128-col panel serves 256 rows).
// ---------------------------------------------------------------------------

typedef _Float16 f16x8 __attribute__((ext_vector_type(8)));
typedef __fp16 fp16x2 __attribute__((ext_vector_type(2)));
typedef float floatx4 __attribute__((ext_vector_type(4)));
typedef unsigned int uint2v __attribute__((ext_vector_type(2)));

union U4H8 { uint4 u; f16x8 h; };

__device__ __forceinline__ ushort f32_to_h_bits(float f) {
  _Float16 h = (_Float16)f;
  return __builtin_bit_cast(ushort, h);
}
__device__ __forceinline__ uint pack2h(float a, float b) {
  return (uint)f32_to_h_bits(a) | ((uint)f32_to_h_bits(b) << 16);
}
__device__ __forceinline__ uint pkrtz(float a, float b) {
  fp16x2 r = __builtin_amdgcn_cvt_pkrtz(a, b);
  return __builtin_bit_cast(uint, r);
}
// bare 2^x (one v_exp_f32, no libm guards)
__device__ __forceinline__ float exp2_fast(float x) {
  float r;
  asm("v_exp_f32 %0, %1" : "=v"(r) : "v"(x));
  return r;
}

// quad-permutation: C-layout quad rows -> B-frag/rowmajor 8-elem runs
// lane(quad,l15) gets elems quad*8+j of the 32-block (proven in R2 P-path).
__device__ __forceinline__ uint4 qtrans(uint pA, uint pB, uint pC, uint pD) {
  uint2v ac = __builtin_amdgcn_permlane32_swap(pA, pC, false, false);
  uint2v bd = __builtin_amdgcn_permlane32_swap(pB, pD, false, false);
  uint2v ac2 = __builtin_amdgcn_permlane16_swap(ac[0], ac[1], false, false);
  uint2v bd2 = __builtin_amdgcn_permlane16_swap(bd[0], bd[1], false, false);
  return (uint4){ac2[0], bd2[0], ac2[1], bd2[1]};
}

// async global->LDS, 16B/lane; LDS dest = wave-uniform base + lane*16
__device__ __forceinline__ void gld16(const void* g, void* l) {
  __builtin_amdgcn_global_load_lds(
      (const __attribute__((address_space(1))) unsigned char*)g,
      (__attribute__((address_space(3))) unsigned char*)l, 16, 0, 0);
}

// ---------------------------------------------------------------- cast kernel
__global__ __launch_bounds__(256) void cast_f32_f16(const float* __restrict__ in,
                                                    ushort* __restrict__ out) {
  int i = blockIdx.x * 256 + threadIdx.x;
  float4 v = ((const float4*)in)[i];
  ushort4 o;
  o.x = f32_to_h_bits(v.x);
  o.y = f32_to_h_bits(v.y);
  o.z = f32_to_h_bits(v.z);
  o.w = f32_to_h_bits(v.w);
  ((ushort4*)out)[i] = o;
}

// ------------------------------------------------------------------ GEMM B^T
// C[M,N] = A[M,K] * B[N,K]^T.  256x128 tile, BK=32, 8 waves (4M x 2N),
// per-wave 64x64 output via 4x4 16x16x32 MFMA frags (same inner loop as the
// proven 128^2 version). Ring-3 LDS pipeline, counted vmcnt (3 loads/wave/
// stage; steady state 6 outstanding -> vmcnt(3)).
// Staging (line-merged + source-swizzled): lane l loads row (granule + l>>2)
// chunk (l&3)^((l>>3)&3) -> linear LDS dest = row-major [row][32] with
// physical chunk p holding logical chunk p^((row>>1)&3).
// Reads: logical chunk quad at row R -> physical quad^((l15>>1)&3).
template <int OUT_F16>
__global__ __launch_bounds__(512) void gemm_bt(const ushort* __restrict__ A,
                                               const ushort* __restrict__ B,
                                               void* __restrict__ Cv,
                                               int M, int N, int K) {
  __shared__ ushort As[3][8192];   // 256 rows x 32, 16 KB per buffer
  __shared__ ushort Bs[3][4096];   // 128 rows x 32,  8 KB per buffer

  const int tid = threadIdx.x;
  const int lane = tid & 63;
  const int w = tid >> 6;          // 0..7
  const int l15 = lane & 15;
  const int quad = lane >> 4;

  // bijective XCD chunk swizzle (requires gx*gy % 8 == 0): XCD k = lin&7
  // owns a contiguous chunk of the linearized grid.
  const int gx = gridDim.x;
  const int lin = blockIdx.y * gx + blockIdx.x;
  const int qq = (gx * gridDim.y) >> 3;
  const int nl = (lin & 7) * qq + (lin >> 3);
  const int m0 = (nl / gx) * 256;
  const int n0 = (nl % gx) * 128;

  const int wm = (w >> 1) * 64;    // 4 M-positions
  const int wn = (w & 1) * 64;     // 2 N-positions

  floatx4 acc[4][4];
#pragma unroll
  for (int i = 0; i < 4; i++)
#pragma unroll
    for (int j = 0; j < 4; j++) acc[i][j] = (floatx4){0.f, 0.f, 0.f, 0.f};

  // staging source: 4 adjacent lanes share one 64B line; chunk XOR-swizzled.
  const int srow = lane >> 2;
  const int sq = ((lane & 3) ^ ((lane >> 3) & 3)) * 8;
  const ushort* Ap0 = A + (size_t)(m0 + w * 32 + srow) * K + sq;
  const ushort* Ap1 = A + (size_t)(m0 + w * 32 + 16 + srow) * K + sq;
  const ushort* Bp = B + (size_t)(n0 + w * 16 + srow) * K + sq;

  auto stage = [&](int k0, int buf) {
    gld16(Ap0 + k0, &As[buf][(2 * w + 0) * 512]);
    gld16(Ap1 + k0, &As[buf][(2 * w + 1) * 512]);
    gld16(Bp + k0, &Bs[buf][w * 512]);
  };

  stage(0, 0);
  stage(32, 1);

  const int psw = (quad ^ ((l15 >> 1) & 3)) * 8;  // physical chunk for reads

  int bt = 0;   // buffer of tile t
  int bs = 2;   // buffer of tile t+2
  for (int k0 = 0; k0 < K; k0 += 32) {
    // steady state: 6 loads outstanding (tiles t, t+1); wait only tile t's 3.
    if (k0 + 64 < K) {
      asm volatile("s_waitcnt vmcnt(3)" ::: "memory");
    } else {
      asm volatile("s_waitcnt vmcnt(0)" ::: "memory");
    }
    __builtin_amdgcn_s_barrier();
    asm volatile("" ::: "memory");
    if (k0 + 64 < K) stage(k0 + 64, bs);

    U4H8 af[4], bf[4];
#pragma unroll
    for (int mi = 0; mi < 4; mi++)
      af[mi].u = *(const uint4*)&As[bt][(wm + mi * 16 + l15) * 32 + psw];
#pragma unroll
    for (int ni = 0; ni < 4; ni++)
      bf[ni].u = *(const uint4*)&Bs[bt][(wn + ni * 16 + l15) * 32 + psw];
#pragma unroll
    for (int mi = 0; mi < 4; mi++)
#pragma unroll
      for (int ni = 0; ni < 4; ni++)
        acc[mi][ni] = __builtin_amdgcn_mfma_f32_16x16x32_f16(af[mi].h, bf[ni].h,
                                                             acc[mi][ni], 0, 0, 0);
    bt = (bt == 2) ? 0 : bt + 1;
    bs = (bs == 2) ? 0 : bs + 1;
  }

#pragma unroll
  for (int mi = 0; mi < 4; mi++) {
#pragma unroll
    for (int r = 0; r < 4; r++) {
      size_t row = m0 + wm + mi * 16 + quad * 4 + r;
#pragma unroll
      for (int ni = 0; ni < 4; ni++) {
        size_t col = n0 + wn + ni * 16 + l15;
        float v = acc[mi][ni][r];
        if (OUT_F16)
          ((ushort*)Cv)[row * N + col] = f32_to_h_bits(v);
        else
          ((float*)Cv)[row * N + col] = v;
      }
    }
  }
}

// --------------------------------------------------------------- V transpose
// qkv [8192][3072] f16 -> vtg[bh=64][dh=64][key=2048] f16.
__global__ __launch_bounds__(256) void vtrans(const ushort* __restrict__ qkv,
                                              ushort* __restrict__ vtg) {
  __shared__ ushort T[64 * 66];
  const int tid = threadIdx.x;
  const int kt = blockIdx.x;
  const int bh = blockIdx.y;
  const int b = bh >> 4, h = bh & 15;

  const int r = tid >> 3;
  const int c = (tid & 7) * 8;
  const ushort* src = qkv + (size_t)(b * 2048 + kt * 64) * 3072 + 2048 + h * 64;
  uint4 v0 = *(const uint4*)(src + (size_t)r * 3072 + c);
  uint4 v1 = *(const uint4*)(src + (size_t)(r + 32) * 3072 + c);
  union { uint4 u; ushort s[8]; } a0, a1;
  a0.u = v0; a1.u = v1;
#pragma unroll
  for (int j = 0; j < 8; j++) {
    T[(c + j) * 66 + r] = a0.s[j];
    T[(c + j) * 66 + r + 32] = a1.s[j];
  }
  __syncthreads();

  const int d = tid >> 3;
  const int kc = (tid & 7) * 8;
  ushort* dst = vtg + (size_t)bh * 64 * 2048 + (size_t)kt * 64;
  union { uint u[4]; uint4 u4; } o0, o1;
#pragma unroll
  for (int i = 0; i < 4; i++) {
    o0.u[i] = *(const uint*)&T[d * 66 + kc + 2 * i];
    o1.u[i] = *(const uint*)&T[(d + 32) * 66 + kc + 2 * i];
  }
  *(uint4*)(dst + (size_t)d * 2048 + kc) = o0.u4;
  *(uint4*)(dst + (size_t)(d + 32) * 2048 + kc) = o1.u4;
}

// ------------------------------------------------------------ flash attention
// Block = strip pair (bx, 31-bx), each strip 64 q; wave w owns q granules.
// 1-D grid 1024; decode: xcd=id&7, n=id>>3, bx=n>>3, bh=xcd*8+(n&7) so each
// XCD works on 8 bh (K/V ~4MB, L2-resident) across all 16 bx.
// K/V double-buffered via gld16; LDS fragment order (sub*64+lane chunks).
// Dual-strip fused step INLINE in the loop (no step lambdas -> no outlining).
__global__ __launch_bounds__(256, 4) void attn_fused(const ushort* __restrict__ qkv,
                                                     const ushort* __restrict__ vtg,
                                                     ushort* __restrict__ attn_out) {
  __shared__ ushort Ks[2][4096];        // [buf][(t*2+kc)*512 + lane*8]  16 KB
  __shared__ ushort Vs[2][4096];        // [buf][(ni*2+kc)*512 + lane*8] 16 KB

  const int tid = threadIdx.x;
  const int lane = tid & 63;
  const int w = tid >> 6;
  const int l15 = lane & 15;
  const int quad = lane >> 4;
  const int id = blockIdx.x;            // 0..1023
  const int n_ = id >> 3;
  const int bx = n_ >> 3;               // 0..15
  const int bh = (id & 7) * 8 + (n_ & 7);
  const int b = bh >> 4;
  const int h = bh & 15;
  const int bS = b * 2048;
  const int qtA = bx;
  const int qtB = 31 - bx;
  const int ktmax = qtB;
  const int q0A = qtA * 64 + w * 16;    // strip 0 q-granule base
  const int q0B = qtB * 64 + w * 16;    // strip 1 q-granule base

  // Q B-frags (B[k=dh][n=q] == Q[q][dh]), pre-scaled by log2(e)/sqrt(64)
  // (exp2-domain softmax: S2 = S * log2e, p = 2^(S2 - m2)).
  U4H8 qf0[2], qf1[2];
  {
    const ushort* qrowA = qkv + (size_t)(bS + q0A + l15) * 3072 + h * 64;
    const ushort* qrowB = qkv + (size_t)(bS + q0B + l15) * 3072 + h * 64;
#pragma unroll
    for (int kc = 0; kc < 2; kc++) {
      qf0[kc].u = *(const uint4*)(qrowA + kc * 32 + quad * 8);
      qf0[kc].h = qf0[kc].h * (_Float16)0.1803368787f;  // 0.125*log2(e)
      qf1[kc].u = *(const uint4*)(qrowB + kc * 32 + quad * 8);
      qf1[kc].h = qf1[kc].h * (_Float16)0.1803368787f;
    }
  }

  floatx4 o0[4], o1[4];  // per strip; D: dh=ni*16+quad*4+r, q=l15
#pragma unroll
  for (int ni = 0; ni < 4; ni++) {
    o0[ni] = (floatx4){0.f, 0.f, 0.f, 0.f};
    o1[ni] = (floatx4){0.f, 0.f, 0.f, 0.f};
  }
  float m0v = -1e30f, m1v = -1e30f, l0v = 0.f, l1v = 0.f;

  const ushort* kbase = qkv + (size_t)bS * 3072 + 1024 + h * 64;
  const ushort* vbase = vtg + (size_t)bh * 64 * 2048;
  const int sr = lane & 15;          // source row within 16-row granule
  const int scc = (lane >> 4) * 8;   // source 8-ushort chunk within 32

  // wave w stages key granule t=w of K and dh granule ni=w of V, in exact
  // fragment-read order (lane l -> row l&15, chunk l>>4).
  auto stage = [&](int kt, int buf) {
    const ushort* kg = kbase + (size_t)(kt * 64 + w * 16 + sr) * 3072 + scc;
    gld16(kg, &Ks[buf][(w * 2 + 0) * 512]);
    gld16(kg + 32, &Ks[buf][(w * 2 + 1) * 512]);
    const ushort* vg = vbase + (size_t)(w * 16 + sr) * 2048 + (size_t)kt * 64 + scc;
    gld16(vg, &Vs[buf][(w * 2 + 0) * 512]);
    gld16(vg + 32, &Vs[buf][(w * 2 + 1) * 512]);
  };

  stage(0, 0);
  for (int kt = 0; kt <= ktmax; ++kt) {
    const int buf = kt & 1;
    __syncthreads();  // drains vmcnt -> buf staged; prior LDS reads done
    if (kt < ktmax) stage(kt + 1, buf ^ 1);
    const bool dual = (kt <= qtA);   // block-uniform
    const int kt64 = kt * 64;

    // ---- St = K Q^T, shared K-frag reads feeding both strips
    floatx4 s1[4], s0[4];
    __builtin_amdgcn_s_setprio(1);
#pragma unroll
    for (int t = 0; t < 4; t++) {
      U4H8 kf0, kf1;
      kf0.u = *(const uint4*)&Ks[buf][(t * 2 + 0) * 512 + lane * 8];
      kf1.u = *(const uint4*)&Ks[buf][(t * 2 + 1) * 512 + lane * 8];
      floatx4 a = (floatx4){0.f, 0.f, 0.f, 0.f};
      a = __builtin_amdgcn_mfma_f32_16x16x32_f16(kf0.h, qf1[0].h, a, 0, 0, 0);
      a = __builtin_amdgcn_mfma_f32_16x16x32_f16(kf1.h, qf1[1].h, a, 0, 0, 0);
      s1[t] = a;
      if (dual) {
        floatx4 c = (floatx4){0.f, 0.f, 0.f, 0.f};
        c = __builtin_amdgcn_mfma_f32_16x16x32_f16(kf0.h, qf0[0].h, c, 0, 0, 0);
        c = __builtin_amdgcn_mfma_f32_16x16x32_f16(kf1.h, qf0[1].h, c, 0, 0, 0);
        s0[t] = c;
      }
    }
    __builtin_amdgcn_s_setprio(0);

    // ---- causal masks (diagonal tiles only)
    if (kt == qtB) {
      const int q = q0B + l15;
#pragma unroll
      for (int t = 0; t < 4; t++)
#pragma unroll
        for (int r = 0; r < 4; r++) {
          int key = kt64 + t * 16 + quad * 4 + r;
          if (key > q) s1[t][r] = -1e30f;
        }
    }
    if (dual && kt == qtA) {
      const int q = q0A + l15;
#pragma unroll
      for (int t = 0; t < 4; t++)
#pragma unroll
        for (int r = 0; r < 4; r++) {
          int key = kt64 + t * 16 + quad * 4 + r;
          if (key > q) s0[t][r] = -1e30f;
        }
    }

    // ---- online softmax strip 1 (always)
    {
      float a1 = fmaxf(fmaxf(s1[0][0], s1[0][1]), fmaxf(s1[0][2], s1[0][3]));
      float b1 = fmaxf(fmaxf(s1[1][0], s1[1][1]), fmaxf(s1[1][2], s1[1][3]));
      float c1 = fmaxf(fmaxf(s1[2][0], s1[2][1]), fmaxf(s1[2][2], s1[2][3]));
      float d1 = fmaxf(fmaxf(s1[3][0], s1[3][1]), fmaxf(s1[3][2], s1[3][3]));
      float t1 = fmaxf(fmaxf(a1, b1), fmaxf(c1, d1));
      t1 = fmaxf(t1, __shfl_xor(t1, 16));
      t1 = fmaxf(t1, __shfl_xor(t1, 32));
      if (__any(t1 > m1v)) {  // defer-max THR=0: alpha==1 exactly when skipped
        float mnew = fmaxf(m1v, t1);
        float alpha = exp2_fast(m1v - mnew);
        m1v = mnew;
        l1v *= alpha;
#pragma unroll
        for (int ni = 0; ni < 4; ni++) o1[ni] *= alpha;
      }
      float rs1 = 0.f;
#pragma unroll
      for (int t = 0; t < 4; t++)
#pragma unroll
        for (int r = 0; r < 4; r++) {
          float p = exp2_fast(s1[t][r] - m1v);
          s1[t][r] = p;
          rs1 += p;
        }
      rs1 += __shfl_xor(rs1, 16);
      rs1 += __shfl_xor(rs1, 32);
      l1v += rs1;
    }
    // ---- online softmax strip 0 (dual only)
    if (dual) {
      float a0 = fmaxf(fmaxf(s0[0][0], s0[0][1]), fmaxf(s0[0][2], s0[0][3]));
      float b0 = fmaxf(fmaxf(s0[1][0], s0[1][1]), fmaxf(s0[1][2], s0[1][3]));
      float c0 = fmaxf(fmaxf(s0[2][0], s0[2][1]), fmaxf(s0[2][2], s0[2][3]));
      float d0 = fmaxf(fmaxf(s0[3][0], s0[3][1]), fmaxf(s0[3][2], s0[3][3]));
      float t0 = fmaxf(fmaxf(a0, b0), fmaxf(c0, d0));
      t0 = fmaxf(t0, __shfl_xor(t0, 16));
      t0 = fmaxf(t0, __shfl_xor(t0, 32));
      if (__any(t0 > m0v)) {
        float mnew = fmaxf(m0v, t0);
        float alpha = exp2_fast(m0v - mnew);
        m0v = mnew;
        l0v *= alpha;
#pragma unroll
        for (int ni = 0; ni < 4; ni++) o0[ni] *= alpha;
      }
      float rs0 = 0.f;
#pragma unroll
      for (int t = 0; t < 4; t++)
#pragma unroll
        for (int r = 0; r < 4; r++) {
          float p = exp2_fast(s0[t][r] - m0v);
          s0[t][r] = p;
          rs0 += p;
        }
      rs0 += __shfl_xor(rs0, 16);
      rs0 += __shfl_xor(rs0, 32);
      l0v += rs0;
    }

    // ---- O^T += V^T P, shared V-frag reads feeding both strips
#pragma unroll
    for (int kc = 0; kc < 2; kc++) {
      U4H8 pb1, pb0;
      pb1.u = qtrans(pkrtz(s1[kc * 2][0], s1[kc * 2][1]),
                     pkrtz(s1[kc * 2][2], s1[kc * 2][3]),
                     pkrtz(s1[kc * 2 + 1][0], s1[kc * 2 + 1][1]),
                     pkrtz(s1[kc * 2 + 1][2], s1[kc * 2 + 1][3]));
      if (dual)
        pb0.u = qtrans(pkrtz(s0[kc * 2][0], s0[kc * 2][1]),
                       pkrtz(s0[kc * 2][2], s0[kc * 2][3]),
                       pkrtz(s0[kc * 2 + 1][0], s0[kc * 2 + 1][1]),
                       pkrtz(s0[kc * 2 + 1][2], s0[kc * 2 + 1][3]));
      __builtin_amdgcn_s_setprio(1);
#pragma unroll
      for (int ni = 0; ni < 4; ni++) {
        U4H8 vf;
        vf.u = *(const uint4*)&Vs[buf][(ni * 2 + kc) * 512 + lane * 8];
        o1[ni] = __builtin_amdgcn_mfma_f32_16x16x32_f16(vf.h, pb1.h, o1[ni], 0, 0, 0);
        if (dual)
          o0[ni] = __builtin_amdgcn_mfma_f32_16x16x32_f16(vf.h, pb0.h, o0[ni], 0, 0, 0);
      }
      __builtin_amdgcn_s_setprio(0);
    }
  }

  // ---- epilogue: O^T -> row-major via qtrans (same permutation as P path);
  // lane(quad,l15) gets dh [p*32+quad*8, +8) of row q0+l15 -> 16B store.
  {
    float inv = 1.0f / l1v;
    ushort* orow = attn_out + (size_t)(bS + q0B + l15) * 1024 + h * 64;
#pragma unroll
    for (int p = 0; p < 2; p++) {
      uint4 x = qtrans(pack2h(o1[p * 2][0] * inv, o1[p * 2][1] * inv),
                       pack2h(o1[p * 2][2] * inv, o1[p * 2][3] * inv),
                       pack2h(o1[p * 2 + 1][0] * inv, o1[p * 2 + 1][1] * inv),
                       pack2h(o1[p * 2 + 1][2] * inv, o1[p * 2 + 1][3] * inv));
      *(uint4*)(orow + p * 32 + quad * 8) = x;
    }
  }
  {
    float inv = 1.0f / l0v;
    ushort* orow = attn_out + (size_t)(bS + q0A + l15) * 1024 + h * 64;
#pragma unroll
    for (int p = 0; p < 2; p++) {
      uint4 x = qtrans(pack2h(o0[p * 2][0] * inv, o0[p * 2][1] * inv),
                       pack2h(o0[p * 2][2] * inv, o0[p * 2][3] * inv),
                       pack2h(o0[p * 2 + 1][0] * inv, o0[p * 2 + 1][1] * inv),
                       pack2h(o0[p * 2 + 1][2] * inv, o0[p * 2 + 1][3] * inv));
      *(uint4*)(orow + p * 32 + quad * 8) = x;
    }
  }
}

// ---------------------------------------------------------------------- launch
extern "C" void kernel_launch(void* const* d_in, const int* in_sizes, int n_in,
                              void* d_out, int out_size, void* d_ws, size_t ws_size,
                              hipStream_t stream) {
  const float* x = (const float*)d_in[0];       // [4,2048,1024]
  const float* wqkv = (const float*)d_in[1];    // [3072,1024]
  const float* wo = (const float*)d_in[2];      // [1024,1024]
  float* out = (float*)d_out;                   // [4,2048,1024] fp32

  ushort* xh = (ushort*)d_ws;                          // 8192*1024
  ushort* wqkvh = xh + (size_t)8192 * 1024;            // 3072*1024
  ushort* woh = wqkvh + (size_t)3072 * 1024;           // 1024*1024
  ushort* qkvh = woh + (size_t)1024 * 1024;            // 8192*3072
  ushort* attnh = qkvh + (size_t)8192 * 3072;          // 8192*1024
  ushort* vtg = attnh + (size_t)8192 * 1024;           // 64*64*2048
  // total ws use: ~109 MB

  cast_f32_f16<<<8192, 256, 0, stream>>>(x, xh);
  cast_f32_f16<<<3072, 256, 0, stream>>>(wqkv, wqkvh);
  cast_f32_f16<<<1024, 256, 0, stream>>>(wo, woh);

  gemm_bt<1><<<dim3(24, 32), 512, 0, stream>>>(xh, wqkvh, qkvh, 8192, 3072, 1024);
  vtrans<<<dim3(32, 64), 256, 0, stream>>>(qkvh, vtg);
  attn_fused<<<dim3(1024), 256, 0, stream>>>(qkvh, vtg, attnh);
  gemm_bt<0><<<dim3(8, 32), 512, 0, stream>>>(attnh, woh, out, 8192, 1024, 1024);
}